// Round 1
// baseline (65.437 us; speedup 1.0000x reference)
//
#include <hip/hip_runtime.h>
#include <hip/hip_bf16.h>

// PositionEmbeddingSine: out[b,c,h,w], c in [0,256).
//   c <  128: k=c,     embed = y_embed[b,h,w]
//   c >= 128: k=c-128, embed = x_embed[b,h,w]
//   val = (k even) ? sin(embed * inv_dim_t[k]) : cos(embed * inv_dim_t[k])
//   inv_dim_t[k] = 10000^(-2*(k/2)/128)
// embeds are normalized cumsums of !mask scaled by 2*pi.

#define BATCH 32
#define HH 96
#define WW 96
#define CC 256
#define F_HALF 128

// log2(10000)
#define LOG2_TEMP 13.287712379549449f
#define TWO_PI 6.2831853071795864769f

// ---------------- kernel 1: masked cumsums -> normalized embeds ----------------
__global__ void pes_cumsum_kernel(const unsigned char* __restrict__ mask,
                                  float* __restrict__ yemb,
                                  float* __restrict__ xemb) {
    int tid = blockIdx.x * blockDim.x + threadIdx.x;
    const float eps = 1e-6f;
    if (tid < BATCH * WW) {
        // y_embed: cumsum along H for fixed (b, w)
        int b = tid / WW, w = tid % WW;
        const unsigned char* m = mask + (size_t)b * HH * WW + w;
        float* o = yemb + (size_t)b * HH * WW + w;
        float s = 0.f;
        float vals[HH];
#pragma unroll
        for (int h = 0; h < HH; ++h) {
            s += (m[h * WW] == 0) ? 1.f : 0.f;
            vals[h] = s;
        }
        float f = TWO_PI / (s + eps);  // s == last element along H
#pragma unroll
        for (int h = 0; h < HH; ++h) o[h * WW] = vals[h] * f;
    } else if (tid < 2 * BATCH * HH) {
        // x_embed: cumsum along W for fixed (b, h)
        int t = tid - BATCH * WW;
        int b = t / HH, h = t % HH;
        const unsigned char* m = mask + ((size_t)b * HH + h) * WW;
        float* o = xemb + ((size_t)b * HH + h) * WW;
        float s = 0.f;
        float vals[WW];
#pragma unroll
        for (int w = 0; w < WW; ++w) {
            s += (m[w] == 0) ? 1.f : 0.f;
            vals[w] = s;
        }
        float f = TWO_PI / (s + eps);  // s == last element along W
#pragma unroll
        for (int w = 0; w < WW; ++w) o[w] = vals[w] * f;
    }
}

// ---------------- kernel 2: generate the positional embedding ----------------
// One float4 (4 consecutive w) per loop iteration; fully coalesced stores.
// total float4 = 32*256*96*24 = 18,874,368
#define W4 (WW / 4)
#define TOTAL4 (BATCH * CC * HH * W4)

__global__ void __launch_bounds__(256)
pes_gen_kernel(const float* __restrict__ yemb,
               const float* __restrict__ xemb,
               float* __restrict__ out) {
    int stride = gridDim.x * blockDim.x;
    for (int i = blockIdx.x * blockDim.x + threadIdx.x; i < TOTAL4; i += stride) {
        int w4 = i % W4;
        int t  = i / W4;
        int h  = t % HH; t /= HH;
        int c  = t % CC;
        int b  = t / CC;

        int k = c & (F_HALF - 1);
        int j = k >> 1;
        // inv_dim_t = 2^(-2*j/128 * log2(10000))
        float inv = exp2f((float)j * (-2.0f / (float)F_HALF) * LOG2_TEMP);

        const float* embbase = (c < F_HALF) ? yemb : xemb;
        const float4 e = *(const float4*)(embbase + ((size_t)b * HH + h) * WW + w4 * 4);

        bool use_sin = (c & 1) == 0;
        float4 r;
        if (use_sin) {
            r.x = __sinf(e.x * inv);
            r.y = __sinf(e.y * inv);
            r.z = __sinf(e.z * inv);
            r.w = __sinf(e.w * inv);
        } else {
            r.x = __cosf(e.x * inv);
            r.y = __cosf(e.y * inv);
            r.z = __cosf(e.z * inv);
            r.w = __cosf(e.w * inv);
        }
        *(float4*)(out + (size_t)i * 4) = r;
    }
}

extern "C" void kernel_launch(void* const* d_in, const int* in_sizes, int n_in,
                              void* d_out, int out_size, void* d_ws, size_t ws_size,
                              hipStream_t stream) {
    // inputs: d_in[0] = x (unused, dtype carrier), d_in[1] = mask (bool, 32*96*96)
    const unsigned char* mask = (const unsigned char*)d_in[1];
    float* out = (float*)d_out;

    // workspace: yemb then xemb, each BATCH*HH*WW floats
    float* yemb = (float*)d_ws;
    float* xemb = yemb + (size_t)BATCH * HH * WW;

    // kernel 1: 2*32*96 = 6144 threads
    {
        int threads = 2 * BATCH * HH;
        int block = 256;
        int grid = (threads + block - 1) / block;
        pes_cumsum_kernel<<<grid, block, 0, stream>>>(mask, yemb, xemb);
    }

    // kernel 2: memory-bound generator, grid-stride
    {
        int block = 256;
        int grid = 2048;  // 256 CU x 8 blocks/CU
        pes_gen_kernel<<<grid, block, 0, stream>>>(yemb, xemb, out);
    }
}